// Round 9
// baseline (49.473 us; speedup 1.0000x reference)
//
#include <hip/hip_runtime.h>
#include <cstddef>

#define PMOD 97
#define HID 512
#define NPAIR 9409
#define NSTEPS 15

typedef __attribute__((ext_vector_type(8))) short short8;
typedef __attribute__((ext_vector_type(4))) short short4_t;
typedef __attribute__((ext_vector_type(4))) float f32x4;

static __device__ __forceinline__ unsigned short f2bf_rn(float f) {
    unsigned u = __float_as_uint(f);
    u += 0x7FFFu + ((u >> 16) & 1u);
    return (unsigned short)(u >> 16);
}
static __device__ __forceinline__ float bf2f(unsigned short h) {
    return __uint_as_float(((unsigned)h) << 16);
}
static __device__ __forceinline__ void split_hilo(const float* __restrict__ p,
                                                  short8& hi, short8& lo) {
    const float4 v0 = *(const float4*)p;
    const float4 v1 = *(const float4*)(p + 4);
    const float vv[8] = {v0.x, v0.y, v0.z, v0.w, v1.x, v1.y, v1.z, v1.w};
#pragma unroll
    for (int q = 0; q < 8; ++q) {
        const unsigned short hb = f2bf_rn(vv[q]);
        hi[q] = (short)hb;
        lo[q] = (short)f2bf_rn(vv[q] - bf2f(hb));
    }
}

// ---------------------------------------------------------------------------
// k_abm: fused W2->bf16 convert + MFMA GEMM for cur1 parts (Ap w/ b1, Bm).
// Unchanged (numerics-preserving). 448 blocks; 4 waves = 4 k-quarters.
// ---------------------------------------------------------------------------
__global__ __launch_bounds__(256) void k_abm(const float* __restrict__ embed,
                                             const float* __restrict__ W1,
                                             const float* __restrict__ W2,
                                             const float* __restrict__ b1,
                                             short* __restrict__ w2bf,
                                             float* __restrict__ Ap,
                                             float* __restrict__ Bm) {
    __shared__ f32x4 red[3][64];   // 3 KB

    const int t = threadIdx.x;
    const int lane = t & 63;
    const int kq = t >> 6;

    const int gid = blockIdx.x * 256 + t;
    if (gid < PMOD * HID / 4) {
        const float4 v = ((const float4*)W2)[gid];
        const float vv[4] = {v.x, v.y, v.z, v.w};
        short4_t h4;
#pragma unroll
        for (int q = 0; q < 4; ++q) h4[q] = (short)f2bf_rn(vv[q]);
        *(short4_t*)(w2bf + gid * 4) = h4;
    }

    const int mt = blockIdx.x >> 6;      // 0..6
    const int ng = blockIdx.x & 63;      // 0..63
    int e = mt * 16 + (lane & 15);
    if (e > PMOD - 1) e = PMOD - 1;
    const int n = ng * 16 + (lane & 15); // 0..1023
    const int h = n & 511;
    const int half = n >> 9;
    const int kbase = kq * 128 + (lane >> 4) * 8;

    f32x4 acc = (f32x4){0.f, 0.f, 0.f, 0.f};
#pragma unroll
    for (int kt = 0; kt < 4; ++kt) {
        const int k = kbase + kt * 32;
        short8 ahi, alo, bhi, blo;
        split_hilo(embed + (size_t)e * HID + k, ahi, alo);
        split_hilo(W1 + (size_t)h * 1024 + half * HID + k, bhi, blo);
        acc = __builtin_amdgcn_mfma_f32_16x16x32_bf16(ahi, bhi, acc, 0, 0, 0);
        acc = __builtin_amdgcn_mfma_f32_16x16x32_bf16(alo, bhi, acc, 0, 0, 0);
        acc = __builtin_amdgcn_mfma_f32_16x16x32_bf16(ahi, blo, acc, 0, 0, 0);
    }

    if (kq != 0) red[kq - 1][lane] = acc;
    __syncthreads();
    if (kq == 0) {
        acc += red[0][lane];
        acc += red[1][lane];
        acc += red[2][lane];
        const float bias = half ? 0.f : b1[h];
#pragma unroll
        for (int reg = 0; reg < 4; ++reg) {
            const int er = mt * 16 + (lane >> 4) * 4 + reg;
            if (er < PMOD) {
                if (half == 0) Ap[(size_t)er * HID + h] = acc[reg] + bias;
                else           Bm[(size_t)er * HID + h] = acc[reg];
            }
        }
    }
}

// ---------------------------------------------------------------------------
// k_sim: LIF simulation only. 2353 blocks x 4 waves; wave = ONE pair,
// lane owns h = lane*8..+7. No LDS, no barriers, 9412 independent waves.
// Same arithmetic as before (bitwise-identical wspk values).
// Writes wspk[pid][512] bf16, 1KB contiguous per wave.
// ---------------------------------------------------------------------------
__global__ __launch_bounds__(256) void k_sim(const float* __restrict__ Ap,
                                             const float* __restrict__ Bm,
                                             const float* __restrict__ pbeta1,
                                             const float* __restrict__ pbeta2,
                                             const float* __restrict__ pthr1,
                                             short* __restrict__ wspk) {
    const float beta1 = fminf(fmaxf(pbeta1[0], 0.1f), 0.9f);
    const float beta2 = fminf(fmaxf(pbeta2[0], 0.1f), 0.9f);
    const float thr   = fmaxf(pthr1[0], 0.1f);

    const int t = threadIdx.x;
    const int lane = t & 63;
    const int w = t >> 6;
    const int pid0 = blockIdx.x * 4 + w;
    const int pid  = (pid0 < NPAIR) ? pid0 : (NPAIR - 1);
    const unsigned i = (unsigned)pid / PMOD;
    const unsigned j = (unsigned)pid - i * PMOD;
    const int h = lane * 8;

    const float* ap = Ap + (size_t)i * HID + h;
    const float* bp = Bm + (size_t)j * HID + h;
    const float4 a0 = *(const float4*)ap;
    const float4 a1 = *(const float4*)(ap + 4);
    const float4 g0 = *(const float4*)bp;
    const float4 g1 = *(const float4*)(bp + 4);
    float c[8] = {a0.x + g0.x, a0.y + g0.y, a0.z + g0.z, a0.w + g0.w,
                  a1.x + g1.x, a1.y + g1.y, a1.z + g1.z, a1.w + g1.w};
    float cm[8], m[8], wv[8];
    bool sb[8];
#pragma unroll
    for (int q = 0; q < 8; ++q) {
        cm[q] = c[q] - thr; m[q] = 0.f; wv[q] = 0.f; sb[q] = false;
    }
    for (int s = 0; s < NSTEPS; ++s) {
#pragma unroll
        for (int q = 0; q < 8; ++q) {
            const float cadj = sb[q] ? cm[q] : c[q];
            m[q] = fmaf(beta1, m[q], cadj);
            sb[q] = m[q] > thr;
            wv[q] = fmaf(beta2, wv[q], sb[q] ? 1.f : 0.f);
        }
    }
    short8 af;
#pragma unroll
    for (int q = 0; q < 8; ++q) af[q] = (short)f2bf_rn(wv[q]);
    *(short8*)(wspk + (size_t)pid * HID + h) = af;   // duplicate pids write identical values
}

// ---------------------------------------------------------------------------
// k_gemm: pairOut = wspk @ w2bf^T + b2*S. 589 blocks x 4 waves = 4 kq.
// A-frags read directly from global wspk (same values v6 had in wfrag);
// accumulation order bitwise-identical to v6 (kt ascending per kq, then
// red[0]+red[1]+red[2]).
// ---------------------------------------------------------------------------
__global__ __launch_bounds__(256) void k_gemm(const short* __restrict__ wspk,
                                              const short* __restrict__ w2bf,
                                              const float* __restrict__ b2,
                                              const float* __restrict__ pbeta2,
                                              float* __restrict__ pairOut) {
    __shared__ f32x4 red[3][7][64];    // 21.5 KB

    const float beta2 = fminf(fmaxf(pbeta2[0], 0.1f), 0.9f);

    const int t = threadIdx.x;
    const int lane = t & 63;
    const int kq = t >> 6;
    const int pblk = blockIdx.x * 16;

    const int pid0 = pblk + (lane & 15);
    const int pidc = (pid0 < NPAIR) ? pid0 : (NPAIR - 1);

    f32x4 acc[7];
#pragma unroll
    for (int nt = 0; nt < 7; ++nt) acc[nt] = (f32x4){0.f, 0.f, 0.f, 0.f};

#pragma unroll
    for (int kk = 0; kk < 4; ++kk) {
        const int kt = kq * 4 + kk;
        const int k = kt * 32 + (lane >> 4) * 8;
        const short8 af = *(const short8*)(wspk + (size_t)pidc * HID + k);
#pragma unroll
        for (int nt = 0; nt < 7; ++nt) {
            const int o0 = nt * 16 + (lane & 15);
            const int oc = (o0 < PMOD) ? o0 : (PMOD - 1);
            const short8 bf = *(const short8*)(w2bf + (size_t)oc * HID + k);
            acc[nt] = __builtin_amdgcn_mfma_f32_16x16x32_bf16(af, bf, acc[nt], 0, 0, 0);
        }
    }

    if (kq != 0) {
#pragma unroll
        for (int nt = 0; nt < 7; ++nt) red[kq - 1][nt][lane] = acc[nt];
    }
    __syncthreads();
    if (kq == 0) {
        float S = 0.f;
#pragma unroll
        for (int s = 0; s < NSTEPS; ++s) S = fmaf(beta2, S, 1.f);
#pragma unroll
        for (int nt = 0; nt < 7; ++nt) {
            f32x4 a = acc[nt];
            a += red[0][nt][lane];
            a += red[1][nt][lane];
            a += red[2][nt][lane];
            const int o = nt * 16 + (lane & 15);
            if (o < PMOD) {
                const float bias = b2[o] * S;
#pragma unroll
                for (int reg = 0; reg < 4; ++reg) {
                    const int prow = pblk + (lane >> 4) * 4 + reg;
                    if (prow < NPAIR)
                        pairOut[(size_t)prow * PMOD + o] = a[reg] + bias;
                }
            }
        }
    }
}

// ---------------------------------------------------------------------------
// k_scatter: out[b][o] = pairOut[x[b,0]*97 + x[b,1]][o]  (coalesced)
// ---------------------------------------------------------------------------
__global__ __launch_bounds__(256) void k_scatter(const int* __restrict__ x,
                                                 const float* __restrict__ pairOut,
                                                 float* __restrict__ out,
                                                 int total) {
    const unsigned idx = blockIdx.x * 256u + threadIdx.x;
    if (idx >= (unsigned)total) return;
    const unsigned b = idx / PMOD;
    const unsigned o = idx - b * PMOD;
    const int pid = x[2 * b] * PMOD + x[2 * b + 1];
    out[idx] = pairOut[(size_t)pid * PMOD + o];
}

// ---------------------------------------------------------------------------
extern "C" void kernel_launch(void* const* d_in, const int* in_sizes, int n_in,
                              void* d_out, int out_size, void* d_ws, size_t ws_size,
                              hipStream_t stream) {
    const int*   x     = (const int*)d_in[0];
    const float* embed = (const float*)d_in[1];
    const float* W1    = (const float*)d_in[2];
    const float* b1    = (const float*)d_in[3];
    const float* W2    = (const float*)d_in[4];
    const float* b2    = (const float*)d_in[5];
    const float* beta1 = (const float*)d_in[6];
    const float* beta2 = (const float*)d_in[7];
    const float* thr1  = (const float*)d_in[8];

    float* out = (float*)d_out;
    const int B = in_sizes[0] / 2;

    // ws layout (13,782,272 B):
    //   0:          pairOut (9409*97*4 = 3,650,816)
    //   3,650,816:  w2bf    (97*512*2 =    99,328)
    //   3,750,144:  Ap      (97*512*4 =   198,656)
    //   3,948,800:  Bm      (97*512*4 =   198,656)
    //   4,147,456:  wspk    (9409*512*2 = 9,634,816)
    char* ws = (char*)d_ws;
    float* pairOut = (float*)(ws);
    short* w2bf    = (short*)(ws + 3650816);
    float* Ap      = (float*)(ws + 3750144);
    float* Bm      = (float*)(ws + 3948800);
    short* wspk    = (short*)(ws + 4147456);

    k_abm<<<448, 256, 0, stream>>>(embed, W1, W2, b1, w2bf, Ap, Bm);

    const int simblk = (NPAIR + 3) / 4;   // 2353 blocks x 4 pair-waves
    k_sim<<<simblk, 256, 0, stream>>>(Ap, Bm, beta1, beta2, thr1, wspk);

    const int nblk = (NPAIR + 15) / 16;   // 589 blocks x 4 kq-waves
    k_gemm<<<nblk, 256, 0, stream>>>(wspk, w2bf, b2, beta2, pairOut);

    const int total = B * PMOD;
    k_scatter<<<(total + 255) / 256, 256, 0, stream>>>(x, pairOut, out, total);
}

// Round 10
// 45.801 us; speedup vs baseline: 1.0802x; 1.0802x over previous
//
#include <hip/hip_runtime.h>
#include <cstddef>

#define PMOD 97
#define HID 512
#define NPAIR 9409
#define NSTEPS 15
#define CAP 64

typedef __attribute__((ext_vector_type(8))) short short8;
typedef __attribute__((ext_vector_type(4))) short short4_t;
typedef __attribute__((ext_vector_type(4))) float f32x4;

static __device__ __forceinline__ unsigned short f2bf_rn(float f) {
    unsigned u = __float_as_uint(f);
    u += 0x7FFFu + ((u >> 16) & 1u);
    return (unsigned short)(u >> 16);
}
static __device__ __forceinline__ float bf2f(unsigned short h) {
    return __uint_as_float(((unsigned)h) << 16);
}
static __device__ __forceinline__ void split_hilo(const float* __restrict__ p,
                                                  short8& hi, short8& lo) {
    const float4 v0 = *(const float4*)p;
    const float4 v1 = *(const float4*)(p + 4);
    const float vv[8] = {v0.x, v0.y, v0.z, v0.w, v1.x, v1.y, v1.z, v1.w};
#pragma unroll
    for (int q = 0; q < 8; ++q) {
        const unsigned short hb = f2bf_rn(vv[q]);
        hi[q] = (short)hb;
        lo[q] = (short)f2bf_rn(vv[q] - bf2f(hb));
    }
}

// ---------------------------------------------------------------------------
// k_abm: fused W2->bf16 convert + MFMA GEMM for cur1 parts (Ap w/ b1, Bm).
// Unchanged from R8 (numerics-preserving). 448 blocks; 4 waves = 4 kq.
// ---------------------------------------------------------------------------
__global__ __launch_bounds__(256) void k_abm(const float* __restrict__ embed,
                                             const float* __restrict__ W1,
                                             const float* __restrict__ W2,
                                             const float* __restrict__ b1,
                                             short* __restrict__ w2bf,
                                             float* __restrict__ Ap,
                                             float* __restrict__ Bm) {
    __shared__ f32x4 red[3][64];   // 3 KB

    const int t = threadIdx.x;
    const int lane = t & 63;
    const int kq = t >> 6;

    const int gid = blockIdx.x * 256 + t;
    if (gid < PMOD * HID / 4) {
        const float4 v = ((const float4*)W2)[gid];
        const float vv[4] = {v.x, v.y, v.z, v.w};
        short4_t h4;
#pragma unroll
        for (int q = 0; q < 4; ++q) h4[q] = (short)f2bf_rn(vv[q]);
        *(short4_t*)(w2bf + gid * 4) = h4;
    }

    const int mt = blockIdx.x >> 6;      // 0..6
    const int ng = blockIdx.x & 63;      // 0..63
    int e = mt * 16 + (lane & 15);
    if (e > PMOD - 1) e = PMOD - 1;
    const int n = ng * 16 + (lane & 15); // 0..1023
    const int h = n & 511;
    const int half = n >> 9;
    const int kbase = kq * 128 + (lane >> 4) * 8;

    f32x4 acc = (f32x4){0.f, 0.f, 0.f, 0.f};
#pragma unroll
    for (int kt = 0; kt < 4; ++kt) {
        const int k = kbase + kt * 32;
        short8 ahi, alo, bhi, blo;
        split_hilo(embed + (size_t)e * HID + k, ahi, alo);
        split_hilo(W1 + (size_t)h * 1024 + half * HID + k, bhi, blo);
        acc = __builtin_amdgcn_mfma_f32_16x16x32_bf16(ahi, bhi, acc, 0, 0, 0);
        acc = __builtin_amdgcn_mfma_f32_16x16x32_bf16(alo, bhi, acc, 0, 0, 0);
        acc = __builtin_amdgcn_mfma_f32_16x16x32_bf16(ahi, blo, acc, 0, 0, 0);
    }

    if (kq != 0) red[kq - 1][lane] = acc;
    __syncthreads();
    if (kq == 0) {
        acc += red[0][lane];
        acc += red[1][lane];
        acc += red[2][lane];
        const float bias = half ? 0.f : b1[h];
#pragma unroll
        for (int reg = 0; reg < 4; ++reg) {
            const int er = mt * 16 + (lane >> 4) * 4 + reg;
            if (er < PMOD) {
                if (half == 0) Ap[(size_t)er * HID + h] = acc[reg] + bias;
                else           Bm[(size_t)er * HID + h] = acc[reg];
            }
        }
    }
}

// ---------------------------------------------------------------------------
// k_mega: v6 k_pairs + in-block x-scan + LDS-staged coalesced scatter.
// 589 blocks x 16 waves (1024 thr).
//   sim: wave w sims k-tile kt=w -> wfrag[kt][lane]  (identical to R8 v6)
//   gemm: wave=(kq=w&3, ns=w>>2), 8 MFMA; then SCAN x for this block's 16
//         pids (LDS atomic push); reduce barrier; kq==0 finalizes into
//         LDS ptile (identical arithmetic to v6's pairOut values).
//   scatter: wave w owns pid-slot w; for each listed b, lanes write
//            out[b][lane] / out[b][64+lane] (388B contiguous per row).
// ---------------------------------------------------------------------------
__global__ __launch_bounds__(1024) void k_mega(const float* __restrict__ Ap,
                                               const float* __restrict__ Bm,
                                               const short* __restrict__ w2bf,
                                               const float* __restrict__ b2,
                                               const float* __restrict__ pbeta1,
                                               const float* __restrict__ pbeta2,
                                               const float* __restrict__ pthr1,
                                               const int* __restrict__ x,
                                               int nB,
                                               float* __restrict__ out) {
    __shared__ short8 wfrag[16][64];   // 16 KB
    __shared__ f32x4 red[3][7][64];    // 21.5 KB
    __shared__ float ptile[16][112];   // 7 KB
    __shared__ int lcnt[16];
    __shared__ int lblist[16][CAP];    // 4 KB

    const float beta1 = fminf(fmaxf(pbeta1[0], 0.1f), 0.9f);
    const float beta2 = fminf(fmaxf(pbeta2[0], 0.1f), 0.9f);
    const float thr   = fmaxf(pthr1[0], 0.1f);

    const int t = threadIdx.x;
    const int lane = t & 63;
    const int w = t >> 6;              // 0..15
    const int pblk = blockIdx.x * 16;

    if (t < 16) lcnt[t] = 0;

    const int pid0 = pblk + (lane & 15);
    const int pid  = (pid0 < NPAIR) ? pid0 : (NPAIR - 1);
    const unsigned i = (unsigned)pid / PMOD;
    const unsigned j = (unsigned)pid - i * PMOD;

    // ---- sim phase: one k-tile per wave ----
    {
        const int kt = w;
        const int h = kt * 32 + (lane >> 4) * 8;
        const float* ap = Ap + (size_t)i * HID + h;
        const float* bp = Bm + (size_t)j * HID + h;
        const float4 a0 = *(const float4*)ap;
        const float4 a1 = *(const float4*)(ap + 4);
        const float4 g0 = *(const float4*)bp;
        const float4 g1 = *(const float4*)(bp + 4);
        float c[8] = {a0.x + g0.x, a0.y + g0.y, a0.z + g0.z, a0.w + g0.w,
                      a1.x + g1.x, a1.y + g1.y, a1.z + g1.z, a1.w + g1.w};
        float cm[8], m[8], wv[8];
        bool sb[8];
#pragma unroll
        for (int q = 0; q < 8; ++q) {
            cm[q] = c[q] - thr; m[q] = 0.f; wv[q] = 0.f; sb[q] = false;
        }
        for (int s = 0; s < NSTEPS; ++s) {
#pragma unroll
            for (int q = 0; q < 8; ++q) {
                const float cadj = sb[q] ? cm[q] : c[q];
                m[q] = fmaf(beta1, m[q], cadj);
                sb[q] = m[q] > thr;
                wv[q] = fmaf(beta2, wv[q], sb[q] ? 1.f : 0.f);
            }
        }
        short8 af;
#pragma unroll
        for (int q = 0; q < 8; ++q) af[q] = (short)f2bf_rn(wv[q]);
        wfrag[kt][lane] = af;
    }
    __syncthreads();   // wfrag + lcnt init visible

    // ---- GEMM phase ----
    const int kq = w & 3;
    const int ns = w >> 2;             // 0..3
    f32x4 acc[2];
#pragma unroll
    for (int q = 0; q < 2; ++q) acc[q] = (f32x4){0.f, 0.f, 0.f, 0.f};

#pragma unroll
    for (int kk = 0; kk < 4; ++kk) {
        const int kt = kq * 4 + kk;
        const short8 af = wfrag[kt][lane];
        const int k = kt * 32 + (lane >> 4) * 8;
#pragma unroll
        for (int q = 0; q < 2; ++q) {
            const int nt = ns * 2 + q;
            if (nt < 7) {
                const int o0 = nt * 16 + (lane & 15);
                const int oc = (o0 < PMOD) ? o0 : (PMOD - 1);
                const short8 bf = *(const short8*)(w2bf + (size_t)oc * HID + k);
                acc[q] = __builtin_amdgcn_mfma_f32_16x16x32_bf16(af, bf, acc[q], 0, 0, 0);
            }
        }
    }

    if (kq != 0) {
#pragma unroll
        for (int q = 0; q < 2; ++q) {
            const int nt = ns * 2 + q;
            if (nt < 7) red[kq - 1][nt][lane] = acc[q];
        }
    }

    // ---- x-scan (overlaps with red[] writes; before reduce barrier) ----
    for (int it = 0; it < 32; ++it) {
        const int b = it * 1024 + t;
        if (b < nB) {
            const int2 xb = ((const int2*)x)[b];
            const int rel = xb.x * PMOD + xb.y - pblk;
            if ((unsigned)rel < 16u) {
                const int slot = atomicAdd(&lcnt[rel], 1);
                if (slot < CAP) lblist[rel][slot] = b;
            }
        }
    }

    __syncthreads();   // red + scan complete

    if (kq == 0) {
        float S = 0.f;
#pragma unroll
        for (int s = 0; s < NSTEPS; ++s) S = fmaf(beta2, S, 1.f);
#pragma unroll
        for (int q = 0; q < 2; ++q) {
            const int nt = ns * 2 + q;
            if (nt < 7) {
                f32x4 a = acc[q];
                a += red[0][nt][lane];
                a += red[1][nt][lane];
                a += red[2][nt][lane];
                const int o = nt * 16 + (lane & 15);
                if (o < PMOD) {
                    const float bias = b2[o] * S;
#pragma unroll
                    for (int reg = 0; reg < 4; ++reg) {
                        const int prow = (lane >> 4) * 4 + reg;   // 0..15
                        ptile[prow][o] = a[reg] + bias;
                    }
                }
            }
        }
    }
    __syncthreads();   // ptile complete

    // ---- scatter: wave w owns pid-slot w ----
    {
        const int nb = lcnt[w];
        const float v0 = ptile[w][lane];                       // o = lane
        const float v1 = (lane < PMOD - 64) ? ptile[w][64 + lane] : 0.f;
        for (int s = 0; s < nb; ++s) {
            const int b = lblist[w][s];
            float* orow = out + (size_t)b * PMOD;
            orow[lane] = v0;
            if (lane < PMOD - 64) orow[64 + lane] = v1;
        }
    }
}

// ---------------------------------------------------------------------------
extern "C" void kernel_launch(void* const* d_in, const int* in_sizes, int n_in,
                              void* d_out, int out_size, void* d_ws, size_t ws_size,
                              hipStream_t stream) {
    const int*   x     = (const int*)d_in[0];
    const float* embed = (const float*)d_in[1];
    const float* W1    = (const float*)d_in[2];
    const float* b1    = (const float*)d_in[3];
    const float* W2    = (const float*)d_in[4];
    const float* b2    = (const float*)d_in[5];
    const float* beta1 = (const float*)d_in[6];
    const float* beta2 = (const float*)d_in[7];
    const float* thr1  = (const float*)d_in[8];

    float* out = (float*)d_out;
    const int B = in_sizes[0] / 2;

    // ws layout (~500 KB):
    //   0:       w2bf (97*512*2 =  99,328)
    //   99,584:  Ap   (97*512*4 = 198,656)
    //   298,496: Bm   (97*512*4 = 198,656)
    char* ws = (char*)d_ws;
    short* w2bf = (short*)(ws);
    float* Ap   = (float*)(ws + 99584);
    float* Bm   = (float*)(ws + 298496);

    k_abm<<<448, 256, 0, stream>>>(embed, W1, W2, b1, w2bf, Ap, Bm);

    const int nblk = (NPAIR + 15) / 16;   // 589 blocks x 16 waves
    k_mega<<<nblk, 1024, 0, stream>>>(Ap, Bm, w2bf, b2, beta1, beta2, thr1,
                                      x, B, out);
}

// Round 11
// 39.736 us; speedup vs baseline: 1.2450x; 1.1526x over previous
//
#include <hip/hip_runtime.h>
#include <cstddef>

#define PMOD 97
#define HID 512
#define NPAIR 9409
#define NSTEPS 15
#define CAP 64

typedef __attribute__((ext_vector_type(8))) short short8;
typedef __attribute__((ext_vector_type(4))) float f32x4;

static __device__ __forceinline__ unsigned short f2bf_rn(float f) {
    unsigned u = __float_as_uint(f);
    u += 0x7FFFu + ((u >> 16) & 1u);
    return (unsigned short)(u >> 16);
}
static __device__ __forceinline__ float bf2f(unsigned short h) {
    return __uint_as_float(((unsigned)h) << 16);
}
static __device__ __forceinline__ void split_hilo(const float* __restrict__ p,
                                                  short8& hi, short8& lo) {
    const float4 v0 = *(const float4*)p;
    const float4 v1 = *(const float4*)(p + 4);
    const float vv[8] = {v0.x, v0.y, v0.z, v0.w, v1.x, v1.y, v1.z, v1.w};
#pragma unroll
    for (int q = 0; q < 8; ++q) {
        const unsigned short hb = f2bf_rn(vv[q]);
        hi[q] = (short)hb;
        lo[q] = (short)f2bf_rn(vv[q] - bf2f(hb));
    }
}

// ---------------------------------------------------------------------------
// k_abm: (a) W2 -> w2f fragment-major bf16 (w2f[kt][nt][lane] = the exact
//        16B chunk the GEMM b-frag lane needs -> k_mega loads are coalesced);
//        (b) inverse index x -> cnt/blist (global, CAP=64);
//        (c) MFMA GEMM for cur1 parts (Ap w/ b1, Bm) — unchanged numerics.
// 448 blocks x 256. cnt[] zeroed by a preceding memset node.
// ---------------------------------------------------------------------------
__global__ __launch_bounds__(256) void k_abm(const float* __restrict__ embed,
                                             const float* __restrict__ W1,
                                             const float* __restrict__ W2,
                                             const float* __restrict__ b1,
                                             const int* __restrict__ x,
                                             int nB,
                                             short* __restrict__ w2f,
                                             int* __restrict__ cnt,
                                             int* __restrict__ blist,
                                             float* __restrict__ Ap,
                                             float* __restrict__ Bm) {
    __shared__ f32x4 red[3][64];   // 3 KB

    const int t = threadIdx.x;
    const int lane = t & 63;
    const int kq = t >> 6;
    const int gid = blockIdx.x * 256 + t;

    // ---- (a) W2 -> w2f: gid in [0, 16*7*64) ----
    if (gid < 16 * 7 * 64) {
        const int kt = gid / 448;
        const int rem = gid - kt * 448;
        const int nt = rem >> 6;
        const int ln = rem & 63;
        int oc = nt * 16 + (ln & 15);
        if (oc > PMOD - 1) oc = PMOD - 1;
        const int k = kt * 32 + (ln >> 4) * 8;
        const float* src = W2 + (size_t)oc * HID + k;
        const float4 v0 = *(const float4*)src;
        const float4 v1 = *(const float4*)(src + 4);
        const float vv[8] = {v0.x, v0.y, v0.z, v0.w, v1.x, v1.y, v1.z, v1.w};
        short8 h8;
#pragma unroll
        for (int q = 0; q < 8; ++q) h8[q] = (short)f2bf_rn(vv[q]);
        *(short8*)(w2f + (size_t)gid * 8) = h8;
    }

    // ---- (b) inverse index ----
    if (gid < nB) {
        const int2 xb = ((const int2*)x)[gid];
        const int pid = xb.x * PMOD + xb.y;
        const int slot = atomicAdd(&cnt[pid], 1);
        if (slot < CAP) blist[pid * CAP + slot] = gid;
    }

    // ---- (c) GEMM (unchanged) ----
    const int mt = blockIdx.x >> 6;      // 0..6
    const int ng = blockIdx.x & 63;      // 0..63
    int e = mt * 16 + (lane & 15);
    if (e > PMOD - 1) e = PMOD - 1;
    const int n = ng * 16 + (lane & 15); // 0..1023
    const int h = n & 511;
    const int half = n >> 9;
    const int kbase = kq * 128 + (lane >> 4) * 8;

    f32x4 acc = (f32x4){0.f, 0.f, 0.f, 0.f};
#pragma unroll
    for (int kt = 0; kt < 4; ++kt) {
        const int k = kbase + kt * 32;
        short8 ahi, alo, bhi, blo;
        split_hilo(embed + (size_t)e * HID + k, ahi, alo);
        split_hilo(W1 + (size_t)h * 1024 + half * HID + k, bhi, blo);
        acc = __builtin_amdgcn_mfma_f32_16x16x32_bf16(ahi, bhi, acc, 0, 0, 0);
        acc = __builtin_amdgcn_mfma_f32_16x16x32_bf16(alo, bhi, acc, 0, 0, 0);
        acc = __builtin_amdgcn_mfma_f32_16x16x32_bf16(ahi, blo, acc, 0, 0, 0);
    }

    if (kq != 0) red[kq - 1][lane] = acc;
    __syncthreads();
    if (kq == 0) {
        acc += red[0][lane];
        acc += red[1][lane];
        acc += red[2][lane];
        const float bias = half ? 0.f : b1[h];
#pragma unroll
        for (int reg = 0; reg < 4; ++reg) {
            const int er = mt * 16 + (lane >> 4) * 4 + reg;
            if (er < PMOD) {
                if (half == 0) Ap[(size_t)er * HID + h] = acc[reg] + bias;
                else           Bm[(size_t)er * HID + h] = acc[reg];
            }
        }
    }
}

// ---------------------------------------------------------------------------
// k_mega v2: all global loads coalesced. 589 blocks x 16 waves.
//   sim: wave w = pair pblk+w (i,j WAVE-UNIFORM -> Ap/Bm rows read as
//        contiguous 2KB). lane owns h=lane*8..+7; identical per-(pid,h)
//        arithmetic -> bitwise-same wspk. Write LDS wkb[m][k] bf16 with
//        XOR swizzle byte^=(m&7)<<4 (conflict-free write, ~free read).
//   gemm: wave=(kq=w&3, ns=w>>2) — EXACT R10 structure/order; a-frag from
//        wkb (LDS), b-frag from w2f (1KB contiguous per wave).
//   epilogue/reduce: verbatim R10 -> ptile.
//   scatter: wave w owns pid-slot w; b-list from global cnt/blist.
// ---------------------------------------------------------------------------
__global__ __launch_bounds__(1024) void k_mega(const float* __restrict__ Ap,
                                               const float* __restrict__ Bm,
                                               const short* __restrict__ w2f,
                                               const float* __restrict__ b2,
                                               const float* __restrict__ pbeta1,
                                               const float* __restrict__ pbeta2,
                                               const float* __restrict__ pthr1,
                                               const int* __restrict__ cnt,
                                               const int* __restrict__ blist,
                                               float* __restrict__ out) {
    __shared__ char wkb[16 * 1024];    // 16 KB, swizzled [m][k] bf16
    __shared__ f32x4 red[3][7][64];    // 21.5 KB
    __shared__ float ptile[16][112];   // 7 KB

    const float beta1 = fminf(fmaxf(pbeta1[0], 0.1f), 0.9f);
    const float beta2 = fminf(fmaxf(pbeta2[0], 0.1f), 0.9f);
    const float thr   = fmaxf(pthr1[0], 0.1f);

    const int t = threadIdx.x;
    const int lane = t & 63;
    const int w = t >> 6;              // 0..15
    const int pblk = blockIdx.x * 16;

    // ---- sim phase: one pair per wave, coalesced reads ----
    {
        int p = pblk + w;
        if (p > NPAIR - 1) p = NPAIR - 1;
        const unsigned i = (unsigned)p / PMOD;
        const unsigned j = (unsigned)p - i * PMOD;
        const float* ap = Ap + (size_t)i * HID + lane * 8;
        const float* bp = Bm + (size_t)j * HID + lane * 8;
        const float4 a0 = *(const float4*)ap;
        const float4 a1 = *(const float4*)(ap + 4);
        const float4 g0 = *(const float4*)bp;
        const float4 g1 = *(const float4*)(bp + 4);
        float c[8] = {a0.x + g0.x, a0.y + g0.y, a0.z + g0.z, a0.w + g0.w,
                      a1.x + g1.x, a1.y + g1.y, a1.z + g1.z, a1.w + g1.w};
        float cm[8], m[8], wv[8];
        bool sb[8];
#pragma unroll
        for (int q = 0; q < 8; ++q) {
            cm[q] = c[q] - thr; m[q] = 0.f; wv[q] = 0.f; sb[q] = false;
        }
        for (int s = 0; s < NSTEPS; ++s) {
#pragma unroll
            for (int q = 0; q < 8; ++q) {
                const float cadj = sb[q] ? cm[q] : c[q];
                m[q] = fmaf(beta1, m[q], cadj);
                sb[q] = m[q] > thr;
                wv[q] = fmaf(beta2, wv[q], sb[q] ? 1.f : 0.f);
            }
        }
        short8 af;
#pragma unroll
        for (int q = 0; q < 8; ++q) af[q] = (short)f2bf_rn(wv[q]);
        // swizzled store: chunk index lane, row w
        *(short8*)(wkb + w * 1024 + ((lane ^ (w & 7)) << 4)) = af;
    }
    __syncthreads();

    // ---- GEMM phase (accumulation order identical to R10) ----
    const int kq = w & 3;
    const int ns = w >> 2;             // 0..3
    const int m16 = lane & 15;
    const int slot = lane >> 4;
    f32x4 acc[2];
#pragma unroll
    for (int q = 0; q < 2; ++q) acc[q] = (f32x4){0.f, 0.f, 0.f, 0.f};

#pragma unroll
    for (int kk = 0; kk < 4; ++kk) {
        const int kt = kq * 4 + kk;
        const short8 af = *(const short8*)(
            wkb + m16 * 1024 + ((((kt << 2) + slot) ^ (m16 & 7)) << 4));
#pragma unroll
        for (int q = 0; q < 2; ++q) {
            const int nt = ns * 2 + q;
            if (nt < 7) {
                const short8 bf = *(const short8*)(
                    w2f + (size_t)((kt * 7 + nt) * 64 + lane) * 8);
                acc[q] = __builtin_amdgcn_mfma_f32_16x16x32_bf16(af, bf, acc[q], 0, 0, 0);
            }
        }
    }

    if (kq != 0) {
#pragma unroll
        for (int q = 0; q < 2; ++q) {
            const int nt = ns * 2 + q;
            if (nt < 7) red[kq - 1][nt][lane] = acc[q];
        }
    }
    __syncthreads();

    if (kq == 0) {
        float S = 0.f;
#pragma unroll
        for (int s = 0; s < NSTEPS; ++s) S = fmaf(beta2, S, 1.f);
#pragma unroll
        for (int q = 0; q < 2; ++q) {
            const int nt = ns * 2 + q;
            if (nt < 7) {
                f32x4 a = acc[q];
                a += red[0][nt][lane];
                a += red[1][nt][lane];
                a += red[2][nt][lane];
                const int o = nt * 16 + (lane & 15);
                if (o < PMOD) {
                    const float bias = b2[o] * S;
#pragma unroll
                    for (int reg = 0; reg < 4; ++reg) {
                        const int prow = (lane >> 4) * 4 + reg;   // 0..15
                        ptile[prow][o] = a[reg] + bias;
                    }
                }
            }
        }
    }
    __syncthreads();

    // ---- scatter: wave w owns pid-slot w ----
    {
        const int p = pblk + w;
        const int nb = (p < NPAIR) ? cnt[p] : 0;
        const float v0 = ptile[w][lane];
        const float v1 = (lane < PMOD - 64) ? ptile[w][64 + lane] : 0.f;
        for (int s = 0; s < nb; ++s) {
            const int b = blist[p * CAP + s];
            float* orow = out + (size_t)b * PMOD;
            orow[lane] = v0;
            if (lane < PMOD - 64) orow[64 + lane] = v1;
        }
    }
}

// ---------------------------------------------------------------------------
extern "C" void kernel_launch(void* const* d_in, const int* in_sizes, int n_in,
                              void* d_out, int out_size, void* d_ws, size_t ws_size,
                              hipStream_t stream) {
    const int*   x     = (const int*)d_in[0];
    const float* embed = (const float*)d_in[1];
    const float* W1    = (const float*)d_in[2];
    const float* b1    = (const float*)d_in[3];
    const float* W2    = (const float*)d_in[4];
    const float* b2    = (const float*)d_in[5];
    const float* beta1 = (const float*)d_in[6];
    const float* beta2 = (const float*)d_in[7];
    const float* thr1  = (const float*)d_in[8];

    float* out = (float*)d_out;
    const int B = in_sizes[0] / 2;

    // ws layout:
    //   0:         cnt   (9409*4 = 37,636; padded to 40,960)
    //   40,960:    blist (9409*64*4 = 2,408,704)
    //   2,449,664: w2f   (16*7*64*8*2 = 114,688)
    //   2,564,352: Ap    (97*512*4 = 198,656)
    //   2,763,008: Bm    (97*512*4 = 198,656)   -> total 2,961,664 B
    char* ws = (char*)d_ws;
    int*   cnt   = (int*)(ws);
    int*   blist = (int*)(ws + 40960);
    short* w2f   = (short*)(ws + 2449664);
    float* Ap    = (float*)(ws + 2564352);
    float* Bm    = (float*)(ws + 2763008);

    hipMemsetAsync(cnt, 0, NPAIR * sizeof(int), stream);

    k_abm<<<448, 256, 0, stream>>>(embed, W1, W2, b1, x, B, w2f, cnt, blist, Ap, Bm);

    const int nblk = (NPAIR + 15) / 16;   // 589 blocks x 16 waves
    k_mega<<<nblk, 1024, 0, stream>>>(Ap, Bm, w2f, b2, beta1, beta2, thr1,
                                      cnt, blist, out);
}